// Round 14
// baseline (534.018 us; speedup 1.0000x reference)
//
#include <hip/hip_runtime.h>

#define BATCH 8
#define SEQ   8192
#define NH    16
#define DP    64
#define DN    64
#define ROWF  (NH*DP)        // 1024 floats per t (all heads)

// ---------------------------------------------------------------------------
// k_partial: ONE WAVE per (b, h, chunk); 16 waves packed into one 1024-thread
// block = (b, chunk) x all heads. The block is purely a RESIDENCY CONTAINER:
// no LDS, no barriers, waves fully independent after the A-scan.
// Rationale (r8-r13 evidence): the CP co-schedules the 16 waves of one big
// block (r13: occ 43.8% = full residency) but never packs >2 small blocks
// (r8/r10/r11/r12 stuck at ~6-8 waves/CU, VALU 34-40%, latency-bound even
// with L3-resident inputs). VGPR budget comes from amdgpu_waves_per_eu(4)
// -> 512/4 = 128 cap (hipcc's __launch_bounds__ 2nd arg maps arg->cap 256/arg
// and capped at 64 whenever >=3: rounds 1,3,6,13 all spilled acc[8][8]).
// partial[p][n] = sum_t exp(chunkTotal - cumsum_t) * X[t][p] * B[t][n]
// ---------------------------------------------------------------------------
template<int NBLK>
__global__ __launch_bounds__(1024)
__attribute__((amdgpu_waves_per_eu(4)))
void k_partial(const float* __restrict__ Xg, const float* __restrict__ Ag,
               const float* __restrict__ Bg, float* __restrict__ part,
               float* __restrict__ blockA)
{
    constexpr int TB = SEQ / NBLK;      // 256 (NBLK=32) or 512 (NBLK=16)
    constexpr int Q  = TB / 64;         // t's per scan-lane: 4 or 8

    const int tid  = threadIdx.x;
    const int lane = tid & 63;
    const int wave = tid >> 6;               // 0..15 == head h
    const int h    = wave;
    const int bc   = blockIdx.x;             // b*NBLK + blk
    const int blk  = bc % NBLK;
    const int b    = bc / NBLK;
    const int t0   = blk * TB;

    // ---- per-wave scan of A column h over this chunk ----
    float c[Q];
    {
        const size_t abase = ((size_t)(b * SEQ + t0 + lane * Q)) * NH + h;
        float run = 0.f;
        #pragma unroll
        for (int k = 0; k < Q; ++k) { run += Ag[abase + (size_t)k * NH]; c[k] = run; }
    }
    float tsum = c[Q - 1], s = tsum;
    #pragma unroll
    for (int d = 1; d < 64; d <<= 1) {
        float o = __shfl_up(s, d, 64);
        if (lane >= d) s += o;
    }
    const float total = __shfl(s, 63, 64);
    const float excl  = s - tsum;
    float wv[Q];                         // weight of t=g*Q+k lives in lane g, reg k
    #pragma unroll
    for (int k = 0; k < Q; ++k) wv[k] = __expf(total - (excl + c[k]));
    if (lane == 63) blockA[(size_t)(b * NH + h) * NBLK + blk] = total;

    // ---- accumulator ----
    float acc[8][8];
    #pragma unroll
    for (int i = 0; i < 8; ++i)
        #pragma unroll
        for (int j = 0; j < 8; ++j) acc[i][j] = 0.f;

    const int p0F = (lane >> 3) << 3;    // this lane's 8 p's
    const int n0F = (lane & 7) << 3;     // this lane's 8 n's

    // 32-bit element indices (X is 67M floats < 2^31)
    const unsigned xb32 = (unsigned)((b * SEQ + t0) * ROWF + h * DP);
    unsigned offX0 = xb32 + p0F;               // even-t set
    unsigned offB0 = xb32 + n0F;
    unsigned offX1 = offX0 + ROWF;             // odd-t set
    unsigned offB1 = offB0 + ROWF;

    // prologue: load t=0 into S0, t=1 into S1
    float4 s0x0 = *(const float4*)(Xg + offX0);
    float4 s0x1 = *(const float4*)(Xg + offX0 + 4);
    float4 s0b0 = *(const float4*)(Bg + offB0);
    float4 s0b1 = *(const float4*)(Bg + offB0 + 4);
    float4 s1x0 = *(const float4*)(Xg + offX1);
    float4 s1x1 = *(const float4*)(Xg + offX1 + 4);
    float4 s1b0 = *(const float4*)(Bg + offB1);
    float4 s1b1 = *(const float4*)(Bg + offB1 + 4);

    auto bodyS0 = [&](float wt, bool reload) {
        const float xs[8] = { s0x0.x * wt, s0x0.y * wt, s0x0.z * wt, s0x0.w * wt,
                              s0x1.x * wt, s0x1.y * wt, s0x1.z * wt, s0x1.w * wt };
        if (reload) {
            offX0 += 2 * ROWF;
            s0x0 = *(const float4*)(Xg + offX0);
            s0x1 = *(const float4*)(Xg + offX0 + 4);
        }
        const float bs[8] = { s0b0.x, s0b0.y, s0b0.z, s0b0.w,
                              s0b1.x, s0b1.y, s0b1.z, s0b1.w };
        #pragma unroll
        for (int i = 0; i < 8; ++i)
            #pragma unroll
            for (int j = 0; j < 8; ++j)
                acc[i][j] = fmaf(xs[i], bs[j], acc[i][j]);
        if (reload) {
            offB0 += 2 * ROWF;
            s0b0 = *(const float4*)(Bg + offB0);
            s0b1 = *(const float4*)(Bg + offB0 + 4);
        }
    };
    auto bodyS1 = [&](float wt, bool reload) {
        const float xs[8] = { s1x0.x * wt, s1x0.y * wt, s1x0.z * wt, s1x0.w * wt,
                              s1x1.x * wt, s1x1.y * wt, s1x1.z * wt, s1x1.w * wt };
        if (reload) {
            offX1 += 2 * ROWF;
            s1x0 = *(const float4*)(Xg + offX1);
            s1x1 = *(const float4*)(Xg + offX1 + 4);
        }
        const float bs[8] = { s1b0.x, s1b0.y, s1b0.z, s1b0.w,
                              s1b1.x, s1b1.y, s1b1.z, s1b1.w };
        #pragma unroll
        for (int i = 0; i < 8; ++i)
            #pragma unroll
            for (int j = 0; j < 8; ++j)
                acc[i][j] = fmaf(xs[i], bs[j], acc[i][j]);
        if (reload) {
            offB1 += 2 * ROWF;
            s1b0 = *(const float4*)(Bg + offB1);
            s1b1 = *(const float4*)(Bg + offB1 + 4);
        }
    };

    // 64 groups of Q t's; weight source lane = g (uniform readlane).
    for (int g = 0; g < 63; ++g) {
        #pragma unroll
        for (int k = 0; k < Q; ++k) {
            const float wt = __shfl(wv[k], g, 64);
            if (k & 1) bodyS1(wt, true);
            else       bodyS0(wt, true);
        }
    }
    {
        const int g = 63;
        #pragma unroll
        for (int k = 0; k < Q; ++k) {
            const float wt = __shfl(wv[k], g, 64);
            if (k & 1) bodyS1(wt, k < Q - 2);
            else       bodyS0(wt, k < Q - 2);
        }
    }

    // ---- epilogue: acc rows are n-contiguous -> float4 stores
    float* dst = part + ((size_t)(b * NH + h) * NBLK + blk) * 4096;
    #pragma unroll
    for (int i = 0; i < 8; ++i) {
        float4 lo = make_float4(acc[i][0], acc[i][1], acc[i][2], acc[i][3]);
        float4 hi = make_float4(acc[i][4], acc[i][5], acc[i][6], acc[i][7]);
        *(float4*)&dst[(p0F + i) * 64 + n0F]     = lo;
        *(float4*)&dst[(p0F + i) * 64 + n0F + 4] = hi;
    }
}

// ---------------------------------------------------------------------------
// k_scales: suffix-exp over chunk totals, per (b,h)
// ---------------------------------------------------------------------------
__global__ void k_scales(const float* __restrict__ blockA, float* __restrict__ scale,
                         int nblk)
{
    const int bh = blockIdx.x * blockDim.x + threadIdx.x;
    if (bh < BATCH * NH) {
        float run = 0.f;
        for (int c2 = nblk - 1; c2 >= 0; --c2) {
            scale[bh * nblk + c2] = __expf(run);
            run += blockA[bh * nblk + c2];
        }
    }
}

// ---------------------------------------------------------------------------
// k_combine: out[bh,p,n] = sum_c scale[bh,c] * part[bh,c,p,n]
// ---------------------------------------------------------------------------
__global__ __launch_bounds__(256)
void k_combine(const float* __restrict__ part, const float* __restrict__ scale,
               float* __restrict__ out, int nblk)
{
    const int idx = blockIdx.x * 256 + threadIdx.x;   // 0..524287
    const int bh  = idx >> 12;
    const int e   = idx & 4095;
    float r = 0.f;
    for (int q = 0; q < nblk; ++q)
        r += scale[bh * nblk + q] * part[((size_t)bh * nblk + q) * 4096 + e];
    out[idx] = r;
}

// ---------------------------------------------------------------------------
extern "C" void kernel_launch(void* const* d_in, const int* in_sizes, int n_in,
                              void* d_out, int out_size, void* d_ws, size_t ws_size,
                              hipStream_t stream)
{
    const float* X = (const float*)d_in[0];
    const float* A = (const float*)d_in[1];
    const float* B = (const float*)d_in[2];
    float* out     = (float*)d_out;

    // ws need for NBLK chunks: part (8*16*NBLK*4096 f32) + blockA + scale
    const size_t need32 = ((size_t)BATCH * NH * 32 * 4096 + 2ull * BATCH * NH * 32) * 4;
    const int nblk = (ws_size >= need32) ? 32 : 16;

    float* part   = (float*)d_ws;
    float* blockA = part + (size_t)BATCH * NH * nblk * 4096;
    float* scale  = blockA + (size_t)BATCH * NH * nblk;

    if (nblk == 32)
        hipLaunchKernelGGL((k_partial<32>), dim3(BATCH * 32), dim3(1024), 0, stream,
                           X, A, B, part, blockA);
    else
        hipLaunchKernelGGL((k_partial<16>), dim3(BATCH * 16), dim3(1024), 0, stream,
                           X, A, B, part, blockA);

    hipLaunchKernelGGL(k_scales, dim3(1), dim3(128), 0, stream, blockA, scale, nblk);
    hipLaunchKernelGGL(k_combine, dim3((BATCH * NH * 4096) / 256), dim3(256), 0, stream,
                       part, scale, out, nblk);
}

// Round 17
// 185.252 us; speedup vs baseline: 2.8827x; 2.8827x over previous
//
#include <hip/hip_runtime.h>

#define BATCH 8
#define SEQ   8192
#define NH    16
#define DP    64
#define DN    64
#define ROWF  (NH*DP)        // 1024 floats = 4KB per t (all heads)
#define HGRP  4              // heads per block
#define NTHR  512            // 8 waves = 4 heads x 2 p-halves
#define TROWS 8              // t-rows staged per tile (8 x 1KB per array)

typedef const __attribute__((address_space(1))) void* gptr_t;
typedef __attribute__((address_space(3))) void* lptr_t;

// ---------------------------------------------------------------------------
// k_partial: block = (b, head-group of 4, chunk); wave = (head, p-half).
// Each wave owns a 32x64 HALF of one head's state -> acc[4][8] = 32 VGPR.
// DESIGNED TO FIT 64 VGPR (see r14 comment block): __launch_bounds__(512,4)
// -> 64-VGPR cap is now the GOAL: 8 waves x 64 VGPR = 512/SIMD exact,
// 4 x 32KB LDS = 128KB -> 4 co-resident blocks = 32 waves/CU.
// r16 BUGFIX: blockA writer is phalf==0 (waves 0,2,4,6 -> heads 0..3), not
// wave==0 (which left heads 1-3 with poisoned workspace -> absmax 11026).
// partial[p][n] = sum_t exp(chunkTotal - cumsum_t) * X[t][p] * B[t][n]
// ---------------------------------------------------------------------------
template<int NBLK>
__global__ __launch_bounds__(NTHR, 4)
void k_partial(const float* __restrict__ Xg, const float* __restrict__ Ag,
               const float* __restrict__ Bg, float* __restrict__ part,
               float* __restrict__ blockA)
{
    constexpr int TB    = SEQ / NBLK;   // 256 (NBLK=32) or 512 (NBLK=16)
    constexpr int Q     = TB / 64;      // A-values per lane in the scan: 4 or 8
    constexpr int NTILE = TB / TROWS;   // 32 or 64

    __shared__ float sX[2][TROWS][HGRP * DP];   // 16 KB
    __shared__ float sB[2][TROWS][HGRP * DP];   // 16 KB (32 KB total)

    const int gid   = blockIdx.x;            // b*(4*NBLK) + hg*NBLK + blk
    const int blk   = gid % NBLK;
    const int hg    = (gid / NBLK) & 3;
    const int b     = gid / (4 * NBLK);
    const int tid   = threadIdx.x;
    const int wave  = tid >> 6;              // 0..7
    const int lane  = tid & 63;
    const int whead = wave >> 1;             // 0..3
    const int phalf = wave & 1;              // 0..1
    const int h     = hg * HGRP + whead;
    const int t0    = blk * TB;

    // ---- per-wave scan of A column h over this chunk (both halves redo it) ----
    float c[Q];
    {
        const size_t abase = ((size_t)(b * SEQ + t0 + lane * Q)) * NH + h;
        float run = 0.f;
        #pragma unroll
        for (int k = 0; k < Q; ++k) { run += Ag[abase + (size_t)k * NH]; c[k] = run; }
    }
    float tsum = c[Q - 1], s = tsum;
    #pragma unroll
    for (int d = 1; d < 64; d <<= 1) {
        float o = __shfl_up(s, d, 64);
        if (lane >= d) s += o;
    }
    const float total = __shfl(s, 63, 64);
    const float excl  = s - tsum;
    float wv[Q];                             // weights stay in registers
    #pragma unroll
    for (int k = 0; k < Q; ++k) wv[k] = __expf(total - (excl + c[k]));
    if (phalf == 0 && lane == 63) blockA[(size_t)(b * NH + h) * NBLK + blk] = total;

    // ---- accumulator: 32x64 half-state, 4 p's x 8 n's per lane ----
    float acc[4][8];
    #pragma unroll
    for (int i = 0; i < 4; ++i)
        #pragma unroll
        for (int j = 0; j < 8; ++j) acc[i][j] = 0.f;

    const int p0 = phalf * 32 + (lane >> 3) * 4;   // 4 p's within head (0..63)
    const int n0 = (lane & 7) * 8;                 // 8 n's
    const int lo4 = lane * 4;                      // lane's 16B in a 1KB segment
    const size_t trow0 = (size_t)(b * SEQ + t0) * ROWF + hg * (HGRP * DP);

    // per tile: 8 rows x 1KB of X and of B = 16 wave-load units; wave w
    // stages X row w and B row w (2 global_load_lds each tile).
    auto stage = [&](int tile, int buf) {
        const int tt = tile % NTILE;               // wrap on last iter
        const size_t rb = trow0 + (size_t)(tt * TROWS + wave) * ROWF + lo4;
        __builtin_amdgcn_global_load_lds((gptr_t)(Xg + rb),
                                         (lptr_t)&sX[buf][wave][0], 16, 0, 0);
        __builtin_amdgcn_global_load_lds((gptr_t)(Bg + rb),
                                         (lptr_t)&sB[buf][wave][0], 16, 0, 0);
    };

    stage(0, 0);
    for (int tile = 0; tile < NTILE; ++tile) {
        const int buf = tile & 1;
        // all 8 waves finished reading buf^1 before overwrite
        asm volatile("s_waitcnt lgkmcnt(0)" ::: "memory");
        __builtin_amdgcn_s_barrier();
        stage((tile + 1) % NTILE, buf ^ 1);
        // wait own 2 loads of CURRENT tile; next tile's 2 stay in flight
        asm volatile("s_waitcnt vmcnt(2)" ::: "memory");
        __builtin_amdgcn_s_barrier();              // tile visible to all

        #pragma unroll
        for (int tt = 0; tt < TROWS; ++tt) {
            const int tglob = tile * TROWS + tt;
            const int srcl  = tglob / Q;                       // uniform lane
            const float wt  = __shfl(wv[tt & (Q - 1)], srcl, 64);
            const float4 xa = *(const float4*)&sX[buf][tt][whead * 64 + p0];
            const float4 ba = *(const float4*)&sB[buf][tt][whead * 64 + n0];
            const float4 bb = *(const float4*)&sB[buf][tt][whead * 64 + n0 + 4];
            const float xs[4] = { xa.x * wt, xa.y * wt, xa.z * wt, xa.w * wt };
            const float bs[8] = { ba.x, ba.y, ba.z, ba.w, bb.x, bb.y, bb.z, bb.w };
            #pragma unroll
            for (int i = 0; i < 4; ++i)
                #pragma unroll
                for (int j = 0; j < 8; ++j)
                    acc[i][j] = fmaf(xs[i], bs[j], acc[i][j]);
        }
    }

    // ---- epilogue: 4 p-rows x 8 n's -> 2 float4 stores per row ----
    float* dst = part + ((size_t)(b * NH + h) * NBLK + blk) * 4096;
    #pragma unroll
    for (int i = 0; i < 4; ++i) {
        float4 lo = make_float4(acc[i][0], acc[i][1], acc[i][2], acc[i][3]);
        float4 hi = make_float4(acc[i][4], acc[i][5], acc[i][6], acc[i][7]);
        *(float4*)&dst[(p0 + i) * 64 + n0]     = lo;
        *(float4*)&dst[(p0 + i) * 64 + n0 + 4] = hi;
    }
}

// ---------------------------------------------------------------------------
// k_scales: suffix-exp over chunk totals, per (b,h)
// ---------------------------------------------------------------------------
__global__ void k_scales(const float* __restrict__ blockA, float* __restrict__ scale,
                         int nblk)
{
    const int bh = blockIdx.x * blockDim.x + threadIdx.x;
    if (bh < BATCH * NH) {
        float run = 0.f;
        for (int c2 = nblk - 1; c2 >= 0; --c2) {
            scale[bh * nblk + c2] = __expf(run);
            run += blockA[bh * nblk + c2];
        }
    }
}

// ---------------------------------------------------------------------------
// k_combine: out[bh,p,n] = sum_c scale[bh,c] * part[bh,c,p,n]
// ---------------------------------------------------------------------------
__global__ __launch_bounds__(256)
void k_combine(const float* __restrict__ part, const float* __restrict__ scale,
               float* __restrict__ out, int nblk)
{
    const int idx = blockIdx.x * 256 + threadIdx.x;   // 0..524287
    const int bh  = idx >> 12;
    const int e   = idx & 4095;
    float r = 0.f;
    for (int q = 0; q < nblk; ++q)
        r += scale[bh * nblk + q] * part[((size_t)bh * nblk + q) * 4096 + e];
    out[idx] = r;
}

// ---------------------------------------------------------------------------
extern "C" void kernel_launch(void* const* d_in, const int* in_sizes, int n_in,
                              void* d_out, int out_size, void* d_ws, size_t ws_size,
                              hipStream_t stream)
{
    const float* X = (const float*)d_in[0];
    const float* A = (const float*)d_in[1];
    const float* B = (const float*)d_in[2];
    float* out     = (float*)d_out;

    // ws need for NBLK chunks: part (8*16*NBLK*4096 f32) + blockA + scale
    const size_t need32 = ((size_t)BATCH * NH * 32 * 4096 + 2ull * BATCH * NH * 32) * 4;
    const int nblk = (ws_size >= need32) ? 32 : 16;

    float* part   = (float*)d_ws;
    float* blockA = part + (size_t)BATCH * NH * nblk * 4096;
    float* scale  = blockA + (size_t)BATCH * NH * nblk;

    if (nblk == 32)
        hipLaunchKernelGGL((k_partial<32>), dim3(BATCH * 4 * 32), dim3(NTHR), 0, stream,
                           X, A, B, part, blockA);
    else
        hipLaunchKernelGGL((k_partial<16>), dim3(BATCH * 4 * 16), dim3(NTHR), 0, stream,
                           X, A, B, part, blockA);

    hipLaunchKernelGGL(k_scales, dim3(1), dim3(128), 0, stream, blockA, scale, nblk);
    hipLaunchKernelGGL(k_combine, dim3((BATCH * NH * 4096) / 256), dim3(256), 0, stream,
                       part, scale, out, nblk);
}

// Round 18
// 142.521 us; speedup vs baseline: 3.7470x; 1.2998x over previous
//
#include <hip/hip_runtime.h>

#define BATCH 8
#define SEQ   8192
#define NH    16
#define DP    64
#define ROWF  (NH*DP)        // 1024 floats = 4KB per t (all heads)
#define HGRP  4              // heads per block
#define NTHR  512            // 8 waves = 4 heads x 2 n-halves
#define KT    32             // t per k-tile = one mfma K-depth
#define RS    257            // dword row-stride in XL/BL ([tp][row] layout)

typedef __attribute__((ext_vector_type(8))) short bf16x8;
typedef __attribute__((ext_vector_type(4))) float f32x4;

// round-to-nearest-even f32->bf16 pair pack: lo -> low 16 bits (even t = lower k)
static __device__ __forceinline__ unsigned pk2(float lo, float hi) {
    unsigned a = __builtin_bit_cast(unsigned, lo);
    unsigned b = __builtin_bit_cast(unsigned, hi);
    a = (a + 0x7FFFu + ((a >> 16) & 1u)) >> 16;
    b = (b + 0x7FFFu + ((b >> 16) & 1u)) & 0xFFFF0000u;
    return (a & 0xFFFFu) | b;
}

// ---------------------------------------------------------------------------
// k_partial (MFMA): per (b,h,chunk): C[64p][64n] = sum_t (w*X)[t][p] * B[t][n]
// == GEMM with K=t. r2-r17 post-mortem: every scalar variant pinned at
// ~205us because the scalar inner loop moves 48B/lane/t through the LDS port
// (~123us/CU of ds_read_b128) regardless of staging/occupancy. MFMA reads
// 16B/lane per 8192-MAC mfma -> ~6x less port traffic, 10x less VALU.
// Pipeline: reg-stage f32 (2 k-tiles deep), mul by w, pack bf16 t-pairs into
// k-major LDS [tp][row], frags = 4 dwords each, 8 mfma per wave per k-tile.
// ---------------------------------------------------------------------------
template<int NBLK>
__global__ __launch_bounds__(NTHR)
void k_partial(const float* __restrict__ Xg, const float* __restrict__ Ag,
               const float* __restrict__ Bg, float* __restrict__ part,
               float* __restrict__ blockA)
{
    constexpr int TB  = SEQ / NBLK;   // 256 (NBLK=32)
    constexpr int Q   = TB / 64;      // 4
    constexpr int NKT = TB / KT;      // 8

    __shared__ unsigned XL[16][RS];   // 16 t-pairs x 256 rows (+pad) of w*X bf16x2
    __shared__ unsigned BL[16][RS];   // same for B
    __shared__ float    WT[HGRP][TB]; // per-head weights for this chunk

    const int gid  = blockIdx.x;            // b*(4*NBLK) + hg*NBLK + blk
    const int blk  = gid % NBLK;
    const int hg   = (gid / NBLK) & 3;
    const int b    = gid / (4 * NBLK);
    const int tid  = threadIdx.x;
    const int w    = tid >> 6;              // 0..7
    const int lane = tid & 63;
    const int hloc = w >> 1;                // head within group
    const int nh   = w & 1;                 // n-half
    const int h    = hg * HGRP + hloc;
    const int t0   = blk * TB;

    // ---- per-wave scan of A column h (redundant across the 2 waves/head) ----
    float c[Q];
    {
        const size_t abase = ((size_t)(b * SEQ + t0 + lane * Q)) * NH + h;
        float run = 0.f;
        #pragma unroll
        for (int k = 0; k < Q; ++k) { run += Ag[abase + (size_t)k * NH]; c[k] = run; }
    }
    float tsum = c[Q - 1], s = tsum;
    #pragma unroll
    for (int d = 1; d < 64; d <<= 1) {
        float o = __shfl_up(s, d, 64);
        if (lane >= d) s += o;
    }
    const float total = __shfl(s, 63, 64);
    const float excl  = s - tsum;
    if (nh == 0) {
        #pragma unroll
        for (int k = 0; k < Q; ++k)
            WT[hloc][lane * Q + k] = __expf(total - (excl + c[k]));
        if (lane == 63) blockA[(size_t)(b * NH + h) * NBLK + blk] = total;
    }

    // ---- accumulators: 4 m-tiles x 2 n-tiles of 16x16 ----
    f32x4 acc[4][2];
    #pragma unroll
    for (int mi = 0; mi < 4; ++mi)
        #pragma unroll
        for (int ni = 0; ni < 2; ++ni) acc[mi][ni] = (f32x4){0.f, 0.f, 0.f, 0.f};

    // staging geometry: one wave-load = one t-row of the 4-head slice (1KB)
    const int hl = lane >> 4;                // head this lane stages
    const int p4 = (lane & 15) * 4;          // 4 consecutive p
    const size_t gbase = (size_t)(b * SEQ + t0) * ROWF + hg * (HGRP * DP) + hl * DP + p4;

    auto issue = [&](int k, float4* lx, float4* lb) {
        if (k >= NKT) return;
        const size_t tb = gbase + (size_t)(k * KT + w * 4) * ROWF;
        #pragma unroll
        for (int i = 0; i < 4; ++i) {
            lx[i] = *(const float4*)(Xg + tb + (size_t)i * ROWF);
            lb[i] = *(const float4*)(Bg + tb + (size_t)i * ROWF);
        }
    };
    auto cwrite = [&](int k, const float4* lx, const float4* lb) {
        const int tIn = k * KT + w * 4;            // within-chunk t of lx[0]
        #pragma unroll
        for (int q = 0; q < 2; ++q) {
            const float w0 = WT[hl][tIn + 2 * q];
            const float w1 = WT[hl][tIn + 2 * q + 1];
            const int   tp = w * 2 + q;            // t-pair slot in tile (0..15)
            const float* x0 = (const float*)&lx[2 * q];
            const float* x1 = (const float*)&lx[2 * q + 1];
            const float* b0 = (const float*)&lb[2 * q];
            const float* b1 = (const float*)&lb[2 * q + 1];
            #pragma unroll
            for (int pp = 0; pp < 4; ++pp) {
                XL[tp][hl * 64 + p4 + pp] = pk2(x0[pp] * w0, x1[pp] * w1);
                BL[tp][hl * 64 + p4 + pp] = pk2(b0[pp], b1[pp]);
            }
        }
    };
    auto compute = [&]() {
        const int r  = lane & 15;
        const int kg = lane >> 4;
        uint4 af[4], bf[2];
        #pragma unroll
        for (int mi = 0; mi < 4; ++mi) {
            const int row = hloc * 64 + mi * 16 + r;
            af[mi].x = XL[kg * 4 + 0][row];
            af[mi].y = XL[kg * 4 + 1][row];
            af[mi].z = XL[kg * 4 + 2][row];
            af[mi].w = XL[kg * 4 + 3][row];
        }
        #pragma unroll
        for (int ni = 0; ni < 2; ++ni) {
            const int row = hloc * 64 + nh * 32 + ni * 16 + r;
            bf[ni].x = BL[kg * 4 + 0][row];
            bf[ni].y = BL[kg * 4 + 1][row];
            bf[ni].z = BL[kg * 4 + 2][row];
            bf[ni].w = BL[kg * 4 + 3][row];
        }
        #pragma unroll
        for (int mi = 0; mi < 4; ++mi) {
            const bf16x8 a = __builtin_bit_cast(bf16x8, af[mi]);
            #pragma unroll
            for (int ni = 0; ni < 2; ++ni) {
                const bf16x8 bb = __builtin_bit_cast(bf16x8, bf[ni]);
                acc[mi][ni] = __builtin_amdgcn_mfma_f32_16x16x32_bf16(
                                  a, bb, acc[mi][ni], 0, 0, 0);
            }
        }
    };

    // ---- pipeline: 2 reg-sets (2 k-tiles in flight), single LDS buffer ----
    float4 sx0[4], sb0[4], sx1[4], sb1[4];
    issue(0, sx0, sb0);
    issue(1, sx1, sb1);
    __syncthreads();                         // WT (and scan) visible

    #pragma unroll 1
    for (int k = 0; k < NKT; k += 2) {
        cwrite(k, sx0, sb0);                 // compiler waits set0's loads
        issue(k + 2, sx0, sb0);
        asm volatile("s_waitcnt lgkmcnt(0)" ::: "memory");
        __builtin_amdgcn_s_barrier();
        __builtin_amdgcn_sched_barrier(0);
        compute();
        __builtin_amdgcn_s_barrier();        // all frag reads done before rewrite

        cwrite(k + 1, sx1, sb1);
        issue(k + 3, sx1, sb1);
        asm volatile("s_waitcnt lgkmcnt(0)" ::: "memory");
        __builtin_amdgcn_s_barrier();
        __builtin_amdgcn_sched_barrier(0);
        compute();
        __builtin_amdgcn_s_barrier();
    }

    // ---- epilogue: C/D layout (m89): col = lane&15, row = (lane>>4)*4 + reg ----
    float* dst = part + ((size_t)(b * NH + h) * NBLK + blk) * 4096;
    {
        const int r  = lane & 15;
        const int cg = lane >> 4;
        #pragma unroll
        for (int mi = 0; mi < 4; ++mi)
            #pragma unroll
            for (int ni = 0; ni < 2; ++ni)
                #pragma unroll
                for (int rr = 0; rr < 4; ++rr)
                    dst[(mi * 16 + cg * 4 + rr) * 64 + nh * 32 + ni * 16 + r] =
                        acc[mi][ni][rr];
    }
}

// ---------------------------------------------------------------------------
// k_scales: suffix-exp over chunk totals, per (b,h)
// ---------------------------------------------------------------------------
__global__ void k_scales(const float* __restrict__ blockA, float* __restrict__ scale,
                         int nblk)
{
    const int bh = blockIdx.x * blockDim.x + threadIdx.x;
    if (bh < BATCH * NH) {
        float run = 0.f;
        for (int c2 = nblk - 1; c2 >= 0; --c2) {
            scale[bh * nblk + c2] = __expf(run);
            run += blockA[bh * nblk + c2];
        }
    }
}

// ---------------------------------------------------------------------------
// k_combine: out[bh,p,n] = sum_c scale[bh,c] * part[bh,c,p,n]
// ---------------------------------------------------------------------------
__global__ __launch_bounds__(256)
void k_combine(const float* __restrict__ part, const float* __restrict__ scale,
               float* __restrict__ out, int nblk)
{
    const int idx = blockIdx.x * 256 + threadIdx.x;   // 0..524287
    const int bh  = idx >> 12;
    const int e   = idx & 4095;
    float r = 0.f;
    for (int q = 0; q < nblk; ++q)
        r += scale[bh * nblk + q] * part[((size_t)bh * nblk + q) * 4096 + e];
    out[idx] = r;
}

// ---------------------------------------------------------------------------
extern "C" void kernel_launch(void* const* d_in, const int* in_sizes, int n_in,
                              void* d_out, int out_size, void* d_ws, size_t ws_size,
                              hipStream_t stream)
{
    const float* X = (const float*)d_in[0];
    const float* A = (const float*)d_in[1];
    const float* B = (const float*)d_in[2];
    float* out     = (float*)d_out;

    const size_t need32 = ((size_t)BATCH * NH * 32 * 4096 + 2ull * BATCH * NH * 32) * 4;
    const int nblk = (ws_size >= need32) ? 32 : 16;

    float* part   = (float*)d_ws;
    float* blockA = part + (size_t)BATCH * NH * nblk * 4096;
    float* scale  = blockA + (size_t)BATCH * NH * nblk;

    if (nblk == 32)
        hipLaunchKernelGGL((k_partial<32>), dim3(BATCH * 4 * 32), dim3(NTHR), 0, stream,
                           X, A, B, part, blockA);
    else
        hipLaunchKernelGGL((k_partial<16>), dim3(BATCH * 4 * 16), dim3(NTHR), 0, stream,
                           X, A, B, part, blockA);

    hipLaunchKernelGGL(k_scales, dim3(1), dim3(128), 0, stream, blockA, scale, nblk);
    hipLaunchKernelGGL(k_combine, dim3((BATCH * NH * 4096) / 256), dim3(256), 0, stream,
                       part, scale, out, nblk);
}